// Round 2
// baseline (3194.285 us; speedup 1.0000x reference)
//
#include <hip/hip_runtime.h>

// ---------------- constants ----------------
#define BB 4
#define TT 1024
#define VV 50257
#define EE 1024
#define HH 16
#define DHD 64
#define NPAD 50304   // 393*128
#define MROWS 4096   // B*T

typedef float f32x4 __attribute__((ext_vector_type(4)));
typedef __bf16 bf16x8 __attribute__((ext_vector_type(8)));

__device__ __forceinline__ float b2f(unsigned short h) {
    unsigned u = ((unsigned)h) << 16;
    return __builtin_bit_cast(float, u);
}
__device__ __forceinline__ unsigned short f2b(float f) {
    unsigned u = __builtin_bit_cast(unsigned, f);
    unsigned r = u + 0x7FFFu + ((u >> 16) & 1u);   // RNE (finite inputs)
    return (unsigned short)(r >> 16);
}

__device__ __forceinline__ void gl_lds16(const void* g, void* l) {
    __builtin_amdgcn_global_load_lds(
        (const __attribute__((address_space(1))) unsigned int*)g,
        (__attribute__((address_space(3))) unsigned int*)l, 16, 0, 0);
}

// swizzle on ushort index within a [rows][64]-bf16 tile: XOR row bits into 16B-chunk bits
__device__ __forceinline__ int swzi(int idx) { return idx ^ (((idx >> 6) & 7) << 3); }

// bijective XCD swizzle; REQUIRES nwg % 8 == 0 (true for both GEMM grids here)
__device__ __forceinline__ int xcd_swz(int bid, int nwg) {
    int cpx = nwg >> 3;
    return (bid & 7) * cpx + (bid >> 3);
}

// ---------------- pack kernels ----------------
// Wq/Wk/Wv [H][E][DH] f32 -> WqkvT bf16 [3072][1024]  (row n: 0..1023=Q(h*64+d),1024..=K,2048..=V)
__global__ __launch_bounds__(256) void pack_qkv(const float* __restrict__ Wq,
                                                const float* __restrict__ Wk,
                                                const float* __restrict__ Wv,
                                                unsigned short* __restrict__ out) {
    long lin = (long)blockIdx.x * 256 + threadIdx.x;      // 3072*1024 total
    int n = (int)(lin >> 10), e = (int)(lin & 1023);
    const float* W = (n < 1024) ? Wq : (n < 2048 ? Wk : Wv);
    int nn = n & 1023, h = nn >> 6, d = nn & 63;
    out[lin] = f2b(W[((long)h * EE + e) * DHD + d]);
}

// W_lm [E][V] f32 -> WlmT bf16 [NPAD][E], zero-padded rows >= V
__global__ __launch_bounds__(256) void pack_lm(const float* __restrict__ W,
                                               unsigned short* __restrict__ Bt) {
    __shared__ float tile[64][65];
    const int tid = threadIdx.x;
    const int v0 = blockIdx.x * 64, e0 = blockIdx.y * 64;
#pragma unroll
    for (int p = 0; p < 4; ++p) {
        int el = p * 16 + (tid >> 4);
        int vl = (tid & 15) * 4;
        const float* src = W + (long)(e0 + el) * VV + v0 + vl;
        float x0 = (v0 + vl + 0 < VV) ? src[0] : 0.f;
        float x1 = (v0 + vl + 1 < VV) ? src[1] : 0.f;
        float x2 = (v0 + vl + 2 < VV) ? src[2] : 0.f;
        float x3 = (v0 + vl + 3 < VV) ? src[3] : 0.f;
        tile[el][vl + 0] = x0; tile[el][vl + 1] = x1;
        tile[el][vl + 2] = x2; tile[el][vl + 3] = x3;
    }
    __syncthreads();
#pragma unroll
    for (int p = 0; p < 4; ++p) {
        int vl = p * 16 + (tid >> 4);
        int el = (tid & 15) * 4;
        ushort4 o;
        o.x = f2b(tile[el + 0][vl]); o.y = f2b(tile[el + 1][vl]);
        o.z = f2b(tile[el + 2][vl]); o.w = f2b(tile[el + 3][vl]);
        *(ushort4*)&Bt[(long)(v0 + vl) * EE + e0 + el] = o;
    }
}

// x = tok_emb[idx] + pos_emb -> bf16 [4096][1024]
__global__ __launch_bounds__(256) void embed_kernel(const int* __restrict__ idx,
                                                    const float* __restrict__ tok,
                                                    const float* __restrict__ pos,
                                                    unsigned short* __restrict__ xb) {
    const int row = blockIdx.x;          // b*T + t
    const int t = row & (TT - 1);
    const int token = idx[row];
    const int c = threadIdx.x * 4;
    float4 a = *(const float4*)&tok[(long)token * EE + c];
    float4 p = *(const float4*)&pos[(long)t * EE + c];
    ushort4 o;
    o.x = f2b(a.x + p.x); o.y = f2b(a.y + p.y);
    o.z = f2b(a.z + p.z); o.w = f2b(a.w + p.w);
    *(ushort4*)&xb[(long)row * EE + c] = o;
}

// ---------------- GEMM: C[M,N] = A[M,K] * Bt[N,K]^T ----------------
// EPI 0: bf16 out, no bias. EPI 1: f32 out + bias + col bound (realN).
template <int EPI>
__global__ __launch_bounds__(256) void gemm_bt(const unsigned short* __restrict__ A,
                                               const unsigned short* __restrict__ B,
                                               void* __restrict__ Cv,
                                               const float* __restrict__ bias,
                                               int K, int numMt, int realN, long ldc,
                                               int nwg) {
    __shared__ __align__(16) unsigned short lA[128 * 64];
    __shared__ __align__(16) unsigned short lB[128 * 64];
    const int tid = threadIdx.x;
    const int lane = tid & 63;
    const int w = tid >> 6;
    const int bid = xcd_swz(blockIdx.x, nwg);
    const int mt = bid % numMt, nt = bid / numMt;
    const long m0 = (long)mt * 128, n0 = (long)nt * 128;

    f32x4 acc[4][4]{};

    for (int k0 = 0; k0 < K; k0 += 64) {
#pragma unroll
        for (int j = 0; j < 4; ++j) {
            int c = j * 256 + tid;
            int cs = c ^ ((c >> 3) & 7);            // pre-swizzled source chunk
            int row = cs >> 3, col = (cs & 7) << 3;
            gl_lds16(A + (m0 + row) * K + (k0 + col), &lA[(j * 4 + w) * 512]);
            gl_lds16(B + (n0 + row) * K + (k0 + col), &lB[(j * 4 + w) * 512]);
        }
        __syncthreads();   // drains vmcnt(0) before barrier
#pragma unroll
        for (int ks = 0; ks < 2; ++ks) {
            bf16x8 af[4], bfr[4];
            const int kcol = ks * 32 + (lane >> 4) * 8;
#pragma unroll
            for (int i = 0; i < 4; ++i) {
                int ar = (w >> 1) * 64 + i * 16 + (lane & 15);
                int br = (w & 1) * 64 + i * 16 + (lane & 15);
                af[i]  = *(const bf16x8*)&lA[swzi(ar * 64 + kcol)];
                bfr[i] = *(const bf16x8*)&lB[swzi(br * 64 + kcol)];
            }
#pragma unroll
            for (int i = 0; i < 4; ++i)
#pragma unroll
                for (int jn = 0; jn < 4; ++jn)
                    acc[i][jn] = __builtin_amdgcn_mfma_f32_16x16x32_bf16(
                        af[i], bfr[jn], acc[i][jn], 0, 0, 0);
        }
        __syncthreads();
    }

    const int lr4 = (lane >> 4) * 4, lc = lane & 15;
#pragma unroll
    for (int i = 0; i < 4; ++i) {
#pragma unroll
        for (int jn = 0; jn < 4; ++jn) {
            long row = m0 + (w >> 1) * 64 + i * 16 + lr4;
            long col = n0 + (w & 1) * 64 + jn * 16 + lc;
#pragma unroll
            for (int r = 0; r < 4; ++r) {
                if (EPI == 0) {
                    ((unsigned short*)Cv)[(row + r) * ldc + col] = f2b(acc[i][jn][r]);
                } else {
                    if (col < realN)
                        ((float*)Cv)[(row + r) * ldc + col] = acc[i][jn][r] + bias[col];
                }
            }
        }
    }
}

// ---------------- attention: flash-style, 1 thread = 1 q row ----------------
__global__ __launch_bounds__(128) void attn_kernel(const unsigned short* __restrict__ qkv,
                                                   unsigned short* __restrict__ outp) {
    __shared__ float Kt[64][68];
    __shared__ float Vt[64][68];
    const int tid = threadIdx.x;
    const int bid = blockIdx.x;
    const int qt = bid & 7, h = (bid >> 3) & 15, b = bid >> 7;
    const int t = qt * 128 + tid;
    const long rowQ = ((long)b * TT + t) * 3072 + h * 64;

    float q[64], o[64];
#pragma unroll
    for (int d = 0; d < 64; d += 4) {
        ushort4 v = *(const ushort4*)&qkv[rowQ + d];
        q[d] = b2f(v.x) * 0.125f; q[d + 1] = b2f(v.y) * 0.125f;
        q[d + 2] = b2f(v.z) * 0.125f; q[d + 3] = b2f(v.w) * 0.125f;
    }
#pragma unroll
    for (int d = 0; d < 64; ++d) o[d] = 0.f;
    float m = -3.0e38f, l = 0.f;

    const int nkt = qt * 2 + 2;
    for (int kt = 0; kt < nkt; ++kt) {
        __syncthreads();
        {
            int r = tid >> 1, ch = (tid & 1) * 32;
            const long base = ((long)b * TT + kt * 64 + r) * 3072 + 1024 + h * 64 + ch;
#pragma unroll
            for (int i = 0; i < 8; ++i) {
                ushort4 kk = *(const ushort4*)&qkv[base + i * 4];
                ushort4 vv = *(const ushort4*)&qkv[base + 1024 + i * 4];
                *(float4*)&Kt[r][ch + i * 4] = make_float4(b2f(kk.x), b2f(kk.y), b2f(kk.z), b2f(kk.w));
                *(float4*)&Vt[r][ch + i * 4] = make_float4(b2f(vv.x), b2f(vv.y), b2f(vv.z), b2f(vv.w));
            }
        }
        __syncthreads();
        const int jmax = min(64, t - kt * 64 + 1);
        for (int j = 0; j < jmax; ++j) {
            float s0 = 0.f, s1 = 0.f, s2 = 0.f, s3 = 0.f;
#pragma unroll
            for (int d = 0; d < 64; d += 4) {
                s0 = fmaf(q[d + 0], Kt[j][d + 0], s0);
                s1 = fmaf(q[d + 1], Kt[j][d + 1], s1);
                s2 = fmaf(q[d + 2], Kt[j][d + 2], s2);
                s3 = fmaf(q[d + 3], Kt[j][d + 3], s3);
            }
            float s = (s0 + s1) + (s2 + s3);
            float mn = fmaxf(m, s);
            float sc = __expf(m - mn);
            float p  = __expf(s - mn);
            l = l * sc + p;
#pragma unroll
            for (int d = 0; d < 64; ++d) o[d] = fmaf(o[d], sc, p * Vt[j][d]);
            m = mn;
        }
    }
    const float inv = 1.f / l;
    const long rowO = ((long)b * TT + t) * EE + h * 64;
#pragma unroll
    for (int d = 0; d < 64; d += 4) {
        ushort4 v;
        v.x = f2b(o[d + 0] * inv); v.y = f2b(o[d + 1] * inv);
        v.z = f2b(o[d + 2] * inv); v.w = f2b(o[d + 3] * inv);
        *(ushort4*)&outp[rowO + d] = v;
    }
}

// ---------------- cross entropy: one block per row ----------------
__global__ __launch_bounds__(256) void ce_kernel(const float* __restrict__ logits,
                                                 const int* __restrict__ targets,
                                                 float* __restrict__ nll) {
    const int row = blockIdx.x;
    const long start = (long)row * VV;
    const int tid = threadIdx.x;
    float m = -3.0e38f, l = 0.f;

    const int pre = (int)((4 - (start & 3)) & 3);
    const long a0 = start + pre;
    const long end = start + VV;
    const long n4 = (end - a0) >> 2;

    if (tid < pre) { m = logits[start + tid]; l = 1.f; }
    for (long i = tid; i < n4; i += 256) {
        float4 v4 = *(const float4*)&logits[a0 + i * 4];
#pragma unroll
        for (int u = 0; u < 4; ++u) {
            float v = (&v4.x)[u];
            float mn = fmaxf(m, v);
            l = l * __expf(m - mn) + __expf(v - mn);
            m = mn;
        }
    }
    const long tstart = a0 + n4 * 4;
    const int tail = (int)(end - tstart);
    if (tid < tail) {
        float v = logits[tstart + tid];
        float mn = fmaxf(m, v);
        l = l * __expf(m - mn) + __expf(v - mn);
        m = mn;
    }
    for (int off = 32; off; off >>= 1) {
        float m2 = __shfl_xor(m, off), l2 = __shfl_xor(l, off);
        float mn = fmaxf(m, m2);
        l = l * __expf(m - mn) + l2 * __expf(m2 - mn);
        m = mn;
    }
    __shared__ float sm[4], sl[4];
    if ((tid & 63) == 0) { sm[tid >> 6] = m; sl[tid >> 6] = l; }
    __syncthreads();
    if (tid == 0) {
        m = sm[0]; l = sl[0];
#pragma unroll
        for (int wv = 1; wv < 4; ++wv) {
            float mn = fmaxf(m, sm[wv]);
            l = l * __expf(m - mn) + sl[wv] * __expf(sm[wv] - mn);
            m = mn;
        }
        nll[row] = m + logf(l) - logits[start + targets[row]];
    }
}

__global__ __launch_bounds__(256) void loss_kernel(const float* __restrict__ nll,
                                                   float* __restrict__ out) {
    const int tid = threadIdx.x;
    float s = 0.f;
    for (int i = tid; i < MROWS; i += 256) s += nll[i];
    for (int off = 32; off; off >>= 1) s += __shfl_xor(s, off);
    __shared__ float sw[4];
    if ((tid & 63) == 0) sw[tid >> 6] = s;
    __syncthreads();
    if (tid == 0) out[0] = (sw[0] + sw[1] + sw[2] + sw[3]) * (1.f / (float)MROWS);
}

// ---------------- launch ----------------
extern "C" void kernel_launch(void* const* d_in, const int* in_sizes, int n_in,
                              void* d_out, int out_size, void* d_ws, size_t ws_size,
                              hipStream_t stream) {
    const int*   idx     = (const int*)d_in[0];
    const int*   targets = (const int*)d_in[1];
    const float* tok     = (const float*)d_in[2];
    const float* pos     = (const float*)d_in[3];
    const float* Wq      = (const float*)d_in[4];
    const float* Wk      = (const float*)d_in[5];
    const float* Wv      = (const float*)d_in[6];
    const float* Wlm     = (const float*)d_in[7];
    const float* blm     = (const float*)d_in[8];
    float* out = (float*)d_out;
    char* ws = (char*)d_ws;

    unsigned short* xb    = (unsigned short*)(ws);                 //  8 MB [4096][1024]
    unsigned short* qkv   = (unsigned short*)(ws + 8388608);       // 24 MB [4096][3072]
    unsigned short* attno = (unsigned short*)(ws + 33554432);      //  8 MB [4096][1024]
    unsigned short* wqkvT = (unsigned short*)(ws + 41943040);      //  6 MB [3072][1024]
    unsigned short* wlmT  = (unsigned short*)(ws + 48234496);      // 98 MB [50304][1024]
    float*          nll   = (float*)(ws + 151257088);              // 16 KB [4096]

    pack_qkv<<<12288, 256, 0, stream>>>(Wq, Wk, Wv, wqkvT);
    pack_lm<<<dim3(NPAD / 64, EE / 64), 256, 0, stream>>>(Wlm, wlmT);
    embed_kernel<<<MROWS, 256, 0, stream>>>(idx, tok, pos, xb);
    // QKV: M=4096, N=3072, K=1024  (nwg=768, %8==0)
    gemm_bt<0><<<32 * 24, 256, 0, stream>>>(xb, wqkvT, qkv, nullptr, EE, 32, 0, 3072, 32 * 24);
    attn_kernel<<<BB * HH * (TT / 128), 128, 0, stream>>>(qkv, attno);
    // LM head: M=4096, N=50304(pad), K=1024, bias, bound V  (nwg=12576, %8==0)
    gemm_bt<1><<<32 * (NPAD / 128), 256, 0, stream>>>(attno, wlmT, out, blm, EE, 32, VV, VV, 32 * (NPAD / 128));
    ce_kernel<<<MROWS, 256, 0, stream>>>(out, targets, nll);
    loss_kernel<<<1, 256, 0, stream>>>(nll, out + (long)MROWS * VV);
}